// Round 9
// baseline (111.097 us; speedup 1.0000x reference)
//
#include <hip/hip_runtime.h>
#include <math.h>

#define BB 8
#define TT 2048
#define CC 1024
#define HH 64
constexpr float SCALE = 0.03125f;              // 1024^-0.5 (reference scales by n_embd)
constexpr float SC2   = 0.03125f * 1.4426950408889634f; // SCALE * log2(e)

typedef __attribute__((ext_vector_type(8))) short bf16x8;
typedef __attribute__((ext_vector_type(8))) short s16x8;
typedef __attribute__((ext_vector_type(4))) short s16x4;
typedef __attribute__((ext_vector_type(4))) float f32x4;

static __device__ __forceinline__ short f2bf(float f) {
    union { float f; unsigned u; } un; un.f = f;
    unsigned r = un.u + 0x7FFFu + ((un.u >> 16) & 1u); // RNE
    return (short)(r >> 16);
}
static __device__ __forceinline__ bf16x8 cat8(s16x4 lo, s16x4 hi) {
    return __builtin_shufflevector(lo, hi, 0, 1, 2, 3, 4, 5, 6, 7);
}

// ---------------- Kernel 1: fused qkv projection, bf16 MFMA ----------------
// Reads x once; computes k,q row-major [b][t][h] bf16 and v TRANSPOSED vT[b][h][t] bf16.
__global__ __launch_bounds__(256) void proj_fused(
    const float* __restrict__ x,
    const float* __restrict__ Wk, const float* __restrict__ Wq, const float* __restrict__ Wv,
    short* __restrict__ ko, short* __restrict__ qo, short* __restrict__ vT)
{
    __shared__ short At[64][68];
    __shared__ short Bt[192][68];

    const int tid  = threadIdx.x;
    const int row0 = blockIdx.x * 64;
    const int wave = tid >> 6, lane = tid & 63;
    const int wm = wave >> 1, wn = wave & 1;
    const int lr = lane & 15, lg = lane >> 4;

    f32x4 acc[2][6] = {};

    for (int k0 = 0; k0 < CC; k0 += 64) {
        __syncthreads();
#pragma unroll
        for (int it = 0; it < 4; ++it) {               // A: 64x64
            int idx = tid + 256 * it;
            int rr = idx >> 4, c4 = (idx & 15) * 4;
            float4 xv = *reinterpret_cast<const float4*>(&x[(size_t)(row0 + rr) * CC + k0 + c4]);
            s16x4 hv = { f2bf(xv.x), f2bf(xv.y), f2bf(xv.z), f2bf(xv.w) };
            *reinterpret_cast<s16x4*>(&At[rr][c4]) = hv;
        }
#pragma unroll
        for (int it = 0; it < 12; ++it) {              // B: 192x64 (Wk|Wq|Wv)
            int idx = tid + 256 * it;
            int rr = idx >> 4, c4 = (idx & 15) * 4;
            const float* Wp = (rr < 64) ? Wk : (rr < 128) ? Wq : Wv;
            int wr = rr & 63;
            float4 wv = *reinterpret_cast<const float4*>(&Wp[(size_t)wr * CC + k0 + c4]);
            s16x4 hw = { f2bf(wv.x), f2bf(wv.y), f2bf(wv.z), f2bf(wv.w) };
            *reinterpret_cast<s16x4*>(&Bt[rr][c4]) = hw;
        }
        __syncthreads();

#pragma unroll
        for (int kk = 0; kk < 64; kk += 32) {
            bf16x8 aF[2], bF[6];
#pragma unroll
            for (int m = 0; m < 2; ++m) {
                int row = wm * 32 + m * 16 + lr;
                aF[m] = cat8(*reinterpret_cast<const s16x4*>(&At[row][kk + 4 * lg]),
                             *reinterpret_cast<const s16x4*>(&At[row][kk + 16 + 4 * lg]));
            }
#pragma unroll
            for (int n = 0; n < 6; ++n) {
                int brow = wn * 96 + n * 16 + lr;
                bF[n] = cat8(*reinterpret_cast<const s16x4*>(&Bt[brow][kk + 4 * lg]),
                             *reinterpret_cast<const s16x4*>(&Bt[brow][kk + 16 + 4 * lg]));
            }
#pragma unroll
            for (int m = 0; m < 2; ++m)
#pragma unroll
                for (int n = 0; n < 6; ++n)
                    acc[m][n] = __builtin_amdgcn_mfma_f32_16x16x32_bf16(aF[m], bF[n], acc[m][n], 0, 0, 0);
        }
    }

    const int bb = row0 >> 11;
    const int t0 = row0 & 2047;
#pragma unroll
    for (int m = 0; m < 2; ++m)
#pragma unroll
        for (int n = 0; n < 6; ++n) {
            const int col0 = wn * 96 + n * 16;
            const int mat  = col0 >> 6;
            const int hcol = (col0 & 63) + lr;
            const int trow = wm * 32 + m * 16 + 4 * lg;
            if (mat == 2) {
                s16x4 pk = { f2bf(acc[m][n][0]), f2bf(acc[m][n][1]),
                             f2bf(acc[m][n][2]), f2bf(acc[m][n][3]) };
                *reinterpret_cast<s16x4*>(&vT[((size_t)bb * HH + hcol) * TT + t0 + trow]) = pk;
            } else {
                short* o = (mat == 0) ? ko : qo;
#pragma unroll
                for (int j = 0; j < 4; ++j)
                    o[(size_t)(row0 + trow + j) * HH + hcol] = f2bf(acc[m][n][j]);
            }
        }
}

// ---------------- Kernel 2: causal flash attention, 1 wave/block, K double-buffered ----------------
// grid 1024 blocks (jq*8 + b) x 64 thr. K-frags prefetched one tile ahead (named bufs);
// V-frags issued at tile top, consumed after softmax.
__global__ __launch_bounds__(64) void attn_reg(
    const short* __restrict__ q, const short* __restrict__ k,
    const short* __restrict__ vT, float* __restrict__ out)
{
    __shared__ short pst[16][76];

    const int lane = threadIdx.x;
    const int blk = blockIdx.x;
    const int b  = blk & 7;
    const int jq = blk >> 3;
    const int q0 = jq * 16;
    const int lr = lane & 15, lg = lane >> 4;

    const short* qb = q  + ((size_t)b * TT + q0) * HH;
    const short* kb = k  + (size_t)b * TT * HH;
    const short* vb = vT + (size_t)b * HH * TT;

    bf16x8 aQ[2];
#pragma unroll
    for (int k2 = 0; k2 < 2; ++k2)
        aQ[k2] = cat8(*reinterpret_cast<const s16x4*>(&qb[lr * HH + k2 * 32 + 4 * lg]),
                      *reinterpret_cast<const s16x4*>(&qb[lr * HH + k2 * 32 + 16 + 4 * lg]));

    f32x4 o[4] = {};
    float m2[4], l_run[4];
#pragma unroll
    for (int j = 0; j < 4; ++j) { m2[j] = -INFINITY; l_run[j] = 0.f; }

    const int ntiles = (jq >> 2) + 1;

#define LOADK(KF, jt) do {                                                          \
    const short* kt_ = kb + (size_t)(jt) * 64 * HH;                                 \
    _Pragma("unroll")                                                               \
    for (int n = 0; n < 4; ++n) {                                                   \
      _Pragma("unroll")                                                             \
      for (int k2 = 0; k2 < 2; ++k2) {                                              \
        const short* kr_ = &kt_[(size_t)(n * 16 + lr) * HH + k2 * 32 + 4 * lg];     \
        KF[n * 2 + k2][0] = *reinterpret_cast<const s16x4*>(kr_);                   \
        KF[n * 2 + k2][1] = *reinterpret_cast<const s16x4*>(kr_ + 16);              \
      }                                                                             \
    }                                                                               \
  } while (0)

#define COMPUTE(KF, jt) do {                                                        \
    const short* vt_ = vb + (jt) * 64;                                              \
    s16x4 vf[8][2];                                                                 \
    _Pragma("unroll")                                                               \
    for (int n = 0; n < 4; ++n) {                                                   \
      _Pragma("unroll")                                                             \
      for (int k2 = 0; k2 < 2; ++k2) {                                              \
        const short* vr_ = &vt_[(size_t)(n * 16 + lr) * TT + k2 * 32 + 4 * lg];     \
        vf[n * 2 + k2][0] = *reinterpret_cast<const s16x4*>(vr_);                   \
        vf[n * 2 + k2][1] = *reinterpret_cast<const s16x4*>(vr_ + 16);              \
      }                                                                             \
    }                                                                               \
    f32x4 s[4] = {};                                                                \
    _Pragma("unroll")                                                               \
    for (int k2 = 0; k2 < 2; ++k2)                                                  \
      _Pragma("unroll")                                                             \
      for (int n = 0; n < 4; ++n)                                                   \
        s[n] = __builtin_amdgcn_mfma_f32_16x16x32_bf16(                             \
            aQ[k2], cat8(KF[n * 2 + k2][0], KF[n * 2 + k2][1]), s[n], 0, 0, 0);     \
    if ((jt) == ntiles - 1) {                                                       \
      _Pragma("unroll")                                                             \
      for (int n = 0; n < 4; ++n)                                                   \
        _Pragma("unroll")                                                           \
        for (int j = 0; j < 4; ++j)                                                 \
          if ((jt) * 64 + n * 16 + lr > q0 + 4 * lg + j) s[n][j] = -3.0e38f;        \
    }                                                                               \
    float tm[4], mnew[4], alpha[4], psum[4];                                        \
    _Pragma("unroll")                                                               \
    for (int j = 0; j < 4; ++j)                                                     \
      tm[j] = fmaxf(fmaxf(s[0][j], s[1][j]), fmaxf(s[2][j], s[3][j]));              \
    _Pragma("unroll")                                                               \
    for (int off = 1; off <= 8; off <<= 1)                                          \
      _Pragma("unroll")                                                             \
      for (int j = 0; j < 4; ++j)                                                   \
        tm[j] = fmaxf(tm[j], __shfl_xor(tm[j], off));                               \
    _Pragma("unroll")                                                               \
    for (int j = 0; j < 4; ++j) {                                                   \
      mnew[j]  = fmaxf(m2[j], tm[j] * SC2);                                         \
      alpha[j] = exp2f(m2[j] - mnew[j]);                                            \
      m2[j]    = mnew[j];                                                           \
      psum[j]  = 0.f;                                                               \
    }                                                                               \
    _Pragma("unroll")                                                               \
    for (int n = 0; n < 4; ++n)                                                     \
      _Pragma("unroll")                                                             \
      for (int j = 0; j < 4; ++j) {                                                 \
        float p = exp2f(fmaf(s[n][j], SC2, -mnew[j]));                              \
        psum[j] += p;                                                               \
        pst[4 * lg + j][n * 16 + lr] = f2bf(p);                                     \
      }                                                                             \
    _Pragma("unroll")                                                               \
    for (int off = 1; off <= 8; off <<= 1)                                          \
      _Pragma("unroll")                                                             \
      for (int j = 0; j < 4; ++j)                                                   \
        psum[j] += __shfl_xor(psum[j], off);                                        \
    _Pragma("unroll")                                                               \
    for (int j = 0; j < 4; ++j)                                                     \
      l_run[j] = l_run[j] * alpha[j] + psum[j];                                     \
    _Pragma("unroll")                                                               \
    for (int n = 0; n < 4; ++n)                                                     \
      _Pragma("unroll")                                                             \
      for (int j = 0; j < 4; ++j)                                                   \
        o[n][j] *= alpha[j];                                                        \
    asm volatile("s_waitcnt lgkmcnt(0)" ::: "memory");                              \
    bf16x8 aP[2];                                                                   \
    _Pragma("unroll")                                                               \
    for (int k2 = 0; k2 < 2; ++k2)                                                  \
      aP[k2] = cat8(*reinterpret_cast<const s16x4*>(&pst[lr][k2 * 32 + 4 * lg]),    \
                    *reinterpret_cast<const s16x4*>(&pst[lr][k2 * 32 + 16 + 4 * lg]));\
    _Pragma("unroll")                                                               \
    for (int k2 = 0; k2 < 2; ++k2)                                                  \
      _Pragma("unroll")                                                             \
      for (int n = 0; n < 4; ++n)                                                   \
        o[n] = __builtin_amdgcn_mfma_f32_16x16x32_bf16(                             \
            aP[k2], cat8(vf[n * 2 + k2][0], vf[n * 2 + k2][1]), o[n], 0, 0, 0);     \
  } while (0)

    s16x4 kfA[8][2], kfB[8][2];
    LOADK(kfA, 0);
    for (int jt = 0; jt < ntiles; jt += 2) {
        if (jt + 1 < ntiles) LOADK(kfB, jt + 1);
        COMPUTE(kfA, jt);
        if (jt + 1 < ntiles) {
            if (jt + 2 < ntiles) LOADK(kfA, jt + 2);
            COMPUTE(kfB, jt + 1);
        }
    }
#undef LOADK
#undef COMPUTE

    float inv[4];
#pragma unroll
    for (int j = 0; j < 4; ++j) inv[j] = 1.f / l_run[j];
    float* ob = out + ((size_t)b * TT + q0) * HH;
#pragma unroll
    for (int n = 0; n < 4; ++n)
#pragma unroll
        for (int j = 0; j < 4; ++j)
            ob[(size_t)(4 * lg + j) * HH + n * 16 + lr] = o[n][j] * inv[j];
}

extern "C" void kernel_launch(void* const* d_in, const int* in_sizes, int n_in,
                              void* d_out, int out_size, void* d_ws, size_t ws_size,
                              hipStream_t stream) {
    const float* x  = (const float*)d_in[0];
    const float* Wk = (const float*)d_in[1];
    const float* Wq = (const float*)d_in[2];
    const float* Wv = (const float*)d_in[3];
    float* outp = (float*)d_out;

    const size_t n = (size_t)BB * TT * HH; // 1,048,576
    short* kbuf = (short*)d_ws;
    short* qbuf = kbuf + n;
    short* vbuf = qbuf + n;   // vT layout [B][H][T]

    proj_fused<<<256, 256, 0, stream>>>(x, Wk, Wq, Wv, kbuf, qbuf, vbuf);
    attn_reg<<<1024, 64, 0, stream>>>(qbuf, kbuf, vbuf, outp);
}

// Round 10
// 111.049 us; speedup vs baseline: 1.0004x; 1.0004x over previous
//
#include <hip/hip_runtime.h>
#include <math.h>

#define BB 8
#define TT 2048
#define CC 1024
#define HH 64
constexpr float SC2 = 0.03125f * 1.4426950408889634f; // (1/sqrt(1024)) * log2(e)

typedef __attribute__((ext_vector_type(8))) short bf16x8;
typedef __attribute__((ext_vector_type(4))) short s16x4;
typedef __attribute__((ext_vector_type(4))) float f32x4;

static __device__ __forceinline__ short f2bf(float f) {
    union { float f; unsigned u; } un; un.f = f;
    unsigned r = un.u + 0x7FFFu + ((un.u >> 16) & 1u); // RNE
    return (short)(r >> 16);
}
static __device__ __forceinline__ bf16x8 cat8(s16x4 lo, s16x4 hi) {
    return __builtin_shufflevector(lo, hi, 0, 1, 2, 3, 4, 5, 6, 7);
}

// ---------------- Kernel 0: W fp32 -> bf16 (once; removes f2bf from proj B-staging) ----------------
__global__ __launch_bounds__(256) void wconv(
    const float* __restrict__ Wk, const float* __restrict__ Wq, const float* __restrict__ Wv,
    short* __restrict__ wbf)
{
    const int i = blockIdx.x * 256 + threadIdx.x;   // 49152 threads, 4 elems each
    const int elem = i * 4;
    const int mat = elem >> 16;                     // 65536 elems per matrix
    const int off = elem & 65535;
    const float* W = (mat == 0) ? Wk : (mat == 1) ? Wq : Wv;
    float4 w4 = *reinterpret_cast<const float4*>(&W[off]);
    s16x4 h = { f2bf(w4.x), f2bf(w4.y), f2bf(w4.z), f2bf(w4.w) };
    *reinterpret_cast<s16x4*>(&wbf[elem]) = h;
}

// ---------------- Kernel 1: fused qkv projection, bf16 MFMA ----------------
// Reads x once; k,q row-major [b][t][h] bf16; v TRANSPOSED vT[b][h][t] bf16.
__global__ __launch_bounds__(256) void proj_fused(
    const float* __restrict__ x, const short* __restrict__ wbf,
    short* __restrict__ ko, short* __restrict__ qo, short* __restrict__ vT)
{
    __shared__ short At[64][68];
    __shared__ short Bt[192][68];

    const int tid  = threadIdx.x;
    const int row0 = blockIdx.x * 64;
    const int wave = tid >> 6, lane = tid & 63;
    const int wm = wave >> 1, wn = wave & 1;
    const int lr = lane & 15, lg = lane >> 4;

    f32x4 acc[2][6] = {};

    for (int k0 = 0; k0 < CC; k0 += 64) {
        __syncthreads();
#pragma unroll
        for (int it = 0; it < 4; ++it) {               // A: 64x64 fp32 -> bf16
            int idx = tid + 256 * it;
            int rr = idx >> 4, c4 = (idx & 15) * 4;
            float4 xv = *reinterpret_cast<const float4*>(&x[(size_t)(row0 + rr) * CC + k0 + c4]);
            s16x4 hv = { f2bf(xv.x), f2bf(xv.y), f2bf(xv.z), f2bf(xv.w) };
            *reinterpret_cast<s16x4*>(&At[rr][c4]) = hv;
        }
#pragma unroll
        for (int it = 0; it < 12; ++it) {              // B: 192x64 bf16 copy (pre-converted)
            int idx = tid + 256 * it;
            int rr = idx >> 4, c4 = (idx & 15) * 4;
            *reinterpret_cast<s16x4*>(&Bt[rr][c4]) =
                *reinterpret_cast<const s16x4*>(&wbf[(size_t)rr * CC + k0 + c4]);
        }
        __syncthreads();

#pragma unroll
        for (int kk = 0; kk < 64; kk += 32) {
            bf16x8 aF[2], bF[6];
#pragma unroll
            for (int m = 0; m < 2; ++m) {
                int row = wm * 32 + m * 16 + lr;
                aF[m] = cat8(*reinterpret_cast<const s16x4*>(&At[row][kk + 4 * lg]),
                             *reinterpret_cast<const s16x4*>(&At[row][kk + 16 + 4 * lg]));
            }
#pragma unroll
            for (int n = 0; n < 6; ++n) {
                int brow = wn * 96 + n * 16 + lr;
                bF[n] = cat8(*reinterpret_cast<const s16x4*>(&Bt[brow][kk + 4 * lg]),
                             *reinterpret_cast<const s16x4*>(&Bt[brow][kk + 16 + 4 * lg]));
            }
#pragma unroll
            for (int m = 0; m < 2; ++m)
#pragma unroll
                for (int n = 0; n < 6; ++n)
                    acc[m][n] = __builtin_amdgcn_mfma_f32_16x16x32_bf16(aF[m], bF[n], acc[m][n], 0, 0, 0);
        }
    }

    const int bb = row0 >> 11;
    const int t0 = row0 & 2047;
#pragma unroll
    for (int m = 0; m < 2; ++m)
#pragma unroll
        for (int n = 0; n < 6; ++n) {
            const int col0 = wn * 96 + n * 16;
            const int mat  = col0 >> 6;
            const int hcol = (col0 & 63) + lr;
            const int trow = wm * 32 + m * 16 + 4 * lg;
            if (mat == 2) {
                s16x4 pk = { f2bf(acc[m][n][0]), f2bf(acc[m][n][1]),
                             f2bf(acc[m][n][2]), f2bf(acc[m][n][3]) };
                *reinterpret_cast<s16x4*>(&vT[((size_t)bb * HH + hcol) * TT + t0 + trow]) = pk;
            } else {
                short* o = (mat == 0) ? ko : qo;
#pragma unroll
                for (int j = 0; j < 4; ++j)
                    o[(size_t)(row0 + trow + j) * HH + hcol] = f2bf(acc[m][n][j]);
            }
        }
}

// ---------------- Kernel 2: causal flash attention, 4 waves/block, kv-split mod 4 ----------------
// grid 1024 blocks (jq*8 + b) x 256 thr. All waves share the 16-row q-tile; wave w does
// kv-tiles jt ≡ w (mod 4) with private (m,l,o); in-LDS merge at the end.
__global__ __launch_bounds__(256) void attn_split(
    const short* __restrict__ q, const short* __restrict__ k,
    const short* __restrict__ vT, float* __restrict__ out)
{
    __shared__ short pst[4][16][76];     // per-wave P round-trip
    __shared__ float ored[4][16][64];    // per-wave partial O
    __shared__ float mred[4][16], lred[4][16];

    const int tid = threadIdx.x;
    const int wv = tid >> 6, lane = tid & 63;
    const int blk = blockIdx.x;
    const int b  = blk & 7;
    const int jq = blk >> 3;
    const int q0 = jq * 16;
    const int lr = lane & 15, lg = lane >> 4;

    const short* qb = q  + ((size_t)b * TT + q0) * HH;
    const short* kb = k  + (size_t)b * TT * HH;
    const short* vb = vT + (size_t)b * HH * TT;

    bf16x8 aQ[2];
#pragma unroll
    for (int k2 = 0; k2 < 2; ++k2)
        aQ[k2] = cat8(*reinterpret_cast<const s16x4*>(&qb[lr * HH + k2 * 32 + 4 * lg]),
                      *reinterpret_cast<const s16x4*>(&qb[lr * HH + k2 * 32 + 16 + 4 * lg]));

    f32x4 o[4] = {};
    float m2[4], l_run[4];
#pragma unroll
    for (int j = 0; j < 4; ++j) { m2[j] = -INFINITY; l_run[j] = 0.f; }

    const int nt = (jq >> 2) + 1;

    for (int jt = wv; jt < nt; jt += 4) {
        const short* kt = kb + (size_t)jt * 64 * HH;
        const short* vt = vb + jt * 64;

        s16x4 kf[8][2], vf[8][2];
#pragma unroll
        for (int n = 0; n < 4; ++n)
#pragma unroll
            for (int k2 = 0; k2 < 2; ++k2) {
                const short* kr = &kt[(size_t)(n * 16 + lr) * HH + k2 * 32 + 4 * lg];
                kf[n * 2 + k2][0] = *reinterpret_cast<const s16x4*>(kr);
                kf[n * 2 + k2][1] = *reinterpret_cast<const s16x4*>(kr + 16);
                const short* vr = &vt[(size_t)(n * 16 + lr) * TT + k2 * 32 + 4 * lg];
                vf[n * 2 + k2][0] = *reinterpret_cast<const s16x4*>(vr);
                vf[n * 2 + k2][1] = *reinterpret_cast<const s16x4*>(vr + 16);
            }

        // S = Q K^T : rows 4lg+j, kv cols n*16+lr
        f32x4 s[4] = {};
#pragma unroll
        for (int k2 = 0; k2 < 2; ++k2)
#pragma unroll
            for (int n = 0; n < 4; ++n)
                s[n] = __builtin_amdgcn_mfma_f32_16x16x32_bf16(
                    aQ[k2], cat8(kf[n * 2 + k2][0], kf[n * 2 + k2][1]), s[n], 0, 0, 0);

        if (jt == nt - 1) { // only the last tile crosses the diagonal
#pragma unroll
            for (int n = 0; n < 4; ++n)
#pragma unroll
                for (int j = 0; j < 4; ++j)
                    if (jt * 64 + n * 16 + lr > q0 + 4 * lg + j) s[n][j] = -3.0e38f;
        }

        float tm[4], mnew[4], alpha[4], psum[4];
#pragma unroll
        for (int j = 0; j < 4; ++j)
            tm[j] = fmaxf(fmaxf(s[0][j], s[1][j]), fmaxf(s[2][j], s[3][j]));
#pragma unroll
        for (int off = 1; off <= 8; off <<= 1)
#pragma unroll
            for (int j = 0; j < 4; ++j)
                tm[j] = fmaxf(tm[j], __shfl_xor(tm[j], off));
#pragma unroll
        for (int j = 0; j < 4; ++j) {
            mnew[j]  = fmaxf(m2[j], tm[j] * SC2);
            alpha[j] = exp2f(m2[j] - mnew[j]);
            m2[j]    = mnew[j];
            psum[j]  = 0.f;
        }
#pragma unroll
        for (int n = 0; n < 4; ++n)
#pragma unroll
            for (int j = 0; j < 4; ++j) {
                float p = exp2f(fmaf(s[n][j], SC2, -mnew[j]));
                psum[j] += p;
                pst[wv][4 * lg + j][n * 16 + lr] = f2bf(p);
            }
#pragma unroll
        for (int off = 1; off <= 8; off <<= 1)
#pragma unroll
            for (int j = 0; j < 4; ++j)
                psum[j] += __shfl_xor(psum[j], off);
#pragma unroll
        for (int j = 0; j < 4; ++j)
            l_run[j] = l_run[j] * alpha[j] + psum[j];
#pragma unroll
        for (int n = 0; n < 4; ++n)
#pragma unroll
            for (int j = 0; j < 4; ++j)
                o[n][j] *= alpha[j];

        asm volatile("s_waitcnt lgkmcnt(0)" ::: "memory");
        bf16x8 aP[2];
#pragma unroll
        for (int k2 = 0; k2 < 2; ++k2)
            aP[k2] = cat8(*reinterpret_cast<const s16x4*>(&pst[wv][lr][k2 * 32 + 4 * lg]),
                          *reinterpret_cast<const s16x4*>(&pst[wv][lr][k2 * 32 + 16 + 4 * lg]));
#pragma unroll
        for (int k2 = 0; k2 < 2; ++k2)
#pragma unroll
            for (int n = 0; n < 4; ++n)
                o[n] = __builtin_amdgcn_mfma_f32_16x16x32_bf16(
                    aP[k2], cat8(vf[n * 2 + k2][0], vf[n * 2 + k2][1]), o[n], 0, 0, 0);
    }

    // ---- write per-wave partials ----
#pragma unroll
    for (int n = 0; n < 4; ++n)
#pragma unroll
        for (int j = 0; j < 4; ++j)
            ored[wv][4 * lg + j][n * 16 + lr] = o[n][j];
    if (lr == 0) {
#pragma unroll
        for (int j = 0; j < 4; ++j) {
            mred[wv][4 * lg + j] = m2[j];
            lred[wv][4 * lg + j] = l_run[j];
        }
    }
    __syncthreads();

    // ---- merge: thread t -> row r=t>>4, cols 4*(t&15).. ----
    const int r = tid >> 4, c0 = (tid & 15) * 4;
    const float M = fmaxf(fmaxf(mred[0][r], mred[1][r]), fmaxf(mred[2][r], mred[3][r]));
    float sc[4], L = 0.f;
#pragma unroll
    for (int w = 0; w < 4; ++w) {
        sc[w] = exp2f(mred[w][r] - M);   // idle wave: exp2(-inf - M) = 0
        L += sc[w] * lred[w][r];
    }
    const float inv = 1.f / L;
    float4 res;
#pragma unroll
    for (int u = 0; u < 4; ++u) {
        float acc = sc[0] * ored[0][r][c0 + u] + sc[1] * ored[1][r][c0 + u]
                  + sc[2] * ored[2][r][c0 + u] + sc[3] * ored[3][r][c0 + u];
        (&res.x)[u] = acc * inv;
    }
    *reinterpret_cast<float4*>(&out[((size_t)b * TT + q0 + r) * HH + c0]) = res;
}

extern "C" void kernel_launch(void* const* d_in, const int* in_sizes, int n_in,
                              void* d_out, int out_size, void* d_ws, size_t ws_size,
                              hipStream_t stream) {
    const float* x  = (const float*)d_in[0];
    const float* Wk = (const float*)d_in[1];
    const float* Wq = (const float*)d_in[2];
    const float* Wv = (const float*)d_in[3];
    float* outp = (float*)d_out;

    const size_t n = (size_t)BB * TT * HH; // 1,048,576
    short* kbuf = (short*)d_ws;
    short* qbuf = kbuf + n;
    short* vbuf = qbuf + n;                 // vT layout [B][H][T]
    short* wbf  = vbuf + n;                 // 3*64*1024 bf16 weights

    wconv<<<192, 256, 0, stream>>>(Wk, Wq, Wv, wbf);
    proj_fused<<<256, 256, 0, stream>>>(x, wbf, kbuf, qbuf, vbuf);
    attn_split<<<1024, 256, 0, stream>>>(qbuf, kbuf, vbuf, outp);
}

// Round 11
// 110.304 us; speedup vs baseline: 1.0072x; 1.0067x over previous
//
#include <hip/hip_runtime.h>
#include <math.h>

#define BB 8
#define TT 2048
#define CC 1024
#define HH 64
constexpr float SC2 = 0.03125f * 1.4426950408889634f; // (1/sqrt(1024)) * log2(e)

typedef __attribute__((ext_vector_type(8))) short bf16x8;
typedef __attribute__((ext_vector_type(4))) short s16x4;
typedef __attribute__((ext_vector_type(4))) float f32x4;

static __device__ __forceinline__ short f2bf(float f) {
    union { float f; unsigned u; } un; un.f = f;
    unsigned r = un.u + 0x7FFFu + ((un.u >> 16) & 1u); // RNE
    return (short)(r >> 16);
}
static __device__ __forceinline__ bf16x8 cat8(s16x4 lo, s16x4 hi) {
    return __builtin_shufflevector(lo, hi, 0, 1, 2, 3, 4, 5, 6, 7);
}

// ---------------- Kernel 0: W fp32 -> bf16 ----------------
__global__ __launch_bounds__(256) void wconv(
    const float* __restrict__ Wk, const float* __restrict__ Wq, const float* __restrict__ Wv,
    short* __restrict__ wbf)
{
    const int i = blockIdx.x * 256 + threadIdx.x;
    const int elem = i * 4;
    const int mat = elem >> 16;
    const int off = elem & 65535;
    const float* W = (mat == 0) ? Wk : (mat == 1) ? Wq : Wv;
    float4 w4 = *reinterpret_cast<const float4*>(&W[off]);
    s16x4 h = { f2bf(w4.x), f2bf(w4.y), f2bf(w4.z), f2bf(w4.w) };
    *reinterpret_cast<s16x4*>(&wbf[elem]) = h;
}

// ---------------- Kernel 1: fused qkv projection, bf16 MFMA ----------------
__global__ __launch_bounds__(256) void proj_fused(
    const float* __restrict__ x, const short* __restrict__ wbf,
    short* __restrict__ ko, short* __restrict__ qo, short* __restrict__ vT)
{
    __shared__ short At[64][68];
    __shared__ short Bt[192][68];

    const int tid  = threadIdx.x;
    const int row0 = blockIdx.x * 64;
    const int wave = tid >> 6, lane = tid & 63;
    const int wm = wave >> 1, wn = wave & 1;
    const int lr = lane & 15, lg = lane >> 4;

    f32x4 acc[2][6] = {};

    for (int k0 = 0; k0 < CC; k0 += 64) {
        __syncthreads();
#pragma unroll
        for (int it = 0; it < 4; ++it) {
            int idx = tid + 256 * it;
            int rr = idx >> 4, c4 = (idx & 15) * 4;
            float4 xv = *reinterpret_cast<const float4*>(&x[(size_t)(row0 + rr) * CC + k0 + c4]);
            s16x4 hv = { f2bf(xv.x), f2bf(xv.y), f2bf(xv.z), f2bf(xv.w) };
            *reinterpret_cast<s16x4*>(&At[rr][c4]) = hv;
        }
#pragma unroll
        for (int it = 0; it < 12; ++it) {
            int idx = tid + 256 * it;
            int rr = idx >> 4, c4 = (idx & 15) * 4;
            *reinterpret_cast<s16x4*>(&Bt[rr][c4]) =
                *reinterpret_cast<const s16x4*>(&wbf[(size_t)rr * CC + k0 + c4]);
        }
        __syncthreads();

#pragma unroll
        for (int kk = 0; kk < 64; kk += 32) {
            bf16x8 aF[2], bF[6];
#pragma unroll
            for (int m = 0; m < 2; ++m) {
                int row = wm * 32 + m * 16 + lr;
                aF[m] = cat8(*reinterpret_cast<const s16x4*>(&At[row][kk + 4 * lg]),
                             *reinterpret_cast<const s16x4*>(&At[row][kk + 16 + 4 * lg]));
            }
#pragma unroll
            for (int n = 0; n < 6; ++n) {
                int brow = wn * 96 + n * 16 + lr;
                bF[n] = cat8(*reinterpret_cast<const s16x4*>(&Bt[brow][kk + 4 * lg]),
                             *reinterpret_cast<const s16x4*>(&Bt[brow][kk + 16 + 4 * lg]));
            }
#pragma unroll
            for (int m = 0; m < 2; ++m)
#pragma unroll
                for (int n = 0; n < 6; ++n)
                    acc[m][n] = __builtin_amdgcn_mfma_f32_16x16x32_bf16(aF[m], bF[n], acc[m][n], 0, 0, 0);
        }
    }

    const int bb = row0 >> 11;
    const int t0 = row0 & 2047;
#pragma unroll
    for (int m = 0; m < 2; ++m)
#pragma unroll
        for (int n = 0; n < 6; ++n) {
            const int col0 = wn * 96 + n * 16;
            const int mat  = col0 >> 6;
            const int hcol = (col0 & 63) + lr;
            const int trow = wm * 32 + m * 16 + 4 * lg;
            if (mat == 2) {
                s16x4 pk = { f2bf(acc[m][n][0]), f2bf(acc[m][n][1]),
                             f2bf(acc[m][n][2]), f2bf(acc[m][n][3]) };
                *reinterpret_cast<s16x4*>(&vT[((size_t)bb * HH + hcol) * TT + t0 + trow]) = pk;
            } else {
                short* o = (mat == 0) ? ko : qo;
#pragma unroll
                for (int j = 0; j < 4; ++j)
                    o[(size_t)(row0 + trow + j) * HH + hcol] = f2bf(acc[m][n][j]);
            }
        }
}

// ---------------- Kernel 2: causal flash attention, swapped-QK^T, kv-split mod 4 ----------------
// grid 1024 blocks (jq*8 + b) x 256 thr; ALL blocks co-resident (17KB LDS, ~110 VGPR).
// Swapped MFMA: lane (lr,lg) holds S[q=lr][kv=n*16+4lg+j] -> softmax in-register,
// P IS the PV A-fragment (no LDS round trip).
__global__ __launch_bounds__(256) void attn_swap(
    const short* __restrict__ q, const short* __restrict__ k,
    const short* __restrict__ vT, float* __restrict__ out)
{
    __shared__ float ored[4][16][64];
    __shared__ float mred[4][16], lred[4][16];

    const int tid = threadIdx.x;
    const int wv = tid >> 6, lane = tid & 63;
    const int blk = blockIdx.x;
    const int b  = blk & 7;
    const int jq = blk >> 3;
    const int q0 = jq * 16;
    const int lr = lane & 15, lg = lane >> 4;

    const short* qb = q  + ((size_t)b * TT + q0) * HH;
    const short* kb = k  + (size_t)b * TT * HH;
    const short* vb = vT + (size_t)b * HH * TT;

    bf16x8 aQ[2]; // B-frag: lane supplies Q[q=lr][h=k2*32+4lg+{0..3,16..19}]
#pragma unroll
    for (int k2 = 0; k2 < 2; ++k2)
        aQ[k2] = cat8(*reinterpret_cast<const s16x4*>(&qb[lr * HH + k2 * 32 + 4 * lg]),
                      *reinterpret_cast<const s16x4*>(&qb[lr * HH + k2 * 32 + 16 + 4 * lg]));

    f32x4 o[4] = {};
    float m2 = -INFINITY, l_run = 0.f; // per-lane scalars: this lane's q-row = lr

    const int nt = (jq >> 2) + 1;

    for (int jt = wv; jt < nt; jt += 4) {
        const short* kt = kb + (size_t)jt * 64 * HH;
        const short* vt = vb + jt * 64;

        // K fragments (A-operand: lane supplies K[kv=n*16+lr][h=...])
        s16x4 kf[8][2];
#pragma unroll
        for (int n = 0; n < 4; ++n)
#pragma unroll
            for (int k2 = 0; k2 < 2; ++k2) {
                const short* kr = &kt[(size_t)(n * 16 + lr) * HH + k2 * 32 + 4 * lg];
                kf[n * 2 + k2][0] = *reinterpret_cast<const s16x4*>(kr);
                kf[n * 2 + k2][1] = *reinterpret_cast<const s16x4*>(kr + 16);
            }

        // S^T = K Q^T : s[n][j] = S[q=lr][kv = jt*64 + n*16 + 4lg + j]
        f32x4 s[4] = {};
#pragma unroll
        for (int k2 = 0; k2 < 2; ++k2)
#pragma unroll
            for (int n = 0; n < 4; ++n)
                s[n] = __builtin_amdgcn_mfma_f32_16x16x32_bf16(
                    cat8(kf[n * 2 + k2][0], kf[n * 2 + k2][1]), aQ[k2], s[n], 0, 0, 0);

        // V fragments issued now (latency covered by softmax); kf dead -> regs reused
        s16x4 vf[8][2];
#pragma unroll
        for (int n = 0; n < 4; ++n)
#pragma unroll
            for (int k2 = 0; k2 < 2; ++k2) {
                const short* vr = &vt[(size_t)(n * 16 + lr) * TT + k2 * 32 + 4 * lg];
                vf[n * 2 + k2][0] = *reinterpret_cast<const s16x4*>(vr);
                vf[n * 2 + k2][1] = *reinterpret_cast<const s16x4*>(vr + 16);
            }

        // causal mask: kv > q  (only last tile crosses diagonal)
        if (jt == nt - 1) {
#pragma unroll
            for (int n = 0; n < 4; ++n)
#pragma unroll
                for (int j = 0; j < 4; ++j)
                    if (jt * 64 + n * 16 + 4 * lg + j > q0 + lr) s[n][j] = -3.0e38f;
        }

        // ---- online softmax: whole row in this lane (16 vals) + 2 shuffle rounds ----
        float tm = fmaxf(fmaxf(fmaxf(s[0][0], s[0][1]), fmaxf(s[0][2], s[0][3])),
                         fmaxf(fmaxf(s[1][0], s[1][1]), fmaxf(s[1][2], s[1][3])));
        tm = fmaxf(tm, fmaxf(fmaxf(fmaxf(s[2][0], s[2][1]), fmaxf(s[2][2], s[2][3])),
                             fmaxf(fmaxf(s[3][0], s[3][1]), fmaxf(s[3][2], s[3][3]))));
        tm = fmaxf(tm, __shfl_xor(tm, 16));
        tm = fmaxf(tm, __shfl_xor(tm, 32));

        const float mnew = fmaxf(m2, tm * SC2);
        const float alpha = exp2f(m2 - mnew); // first tile: exp2(-inf)=0
        m2 = mnew;

        float psum = 0.f;
#pragma unroll
        for (int n = 0; n < 4; ++n)
#pragma unroll
            for (int j = 0; j < 4; ++j) {
                float p = exp2f(fmaf(s[n][j], SC2, -mnew));
                s[n][j] = p;
                psum += p;
            }
        psum += __shfl_xor(psum, 16);
        psum += __shfl_xor(psum, 32);
        l_run = l_run * alpha + psum;

        // rescale O: o[n][j] is row q=4lg+j -> fetch that row's alpha
        float alj[4];
#pragma unroll
        for (int j = 0; j < 4; ++j) alj[j] = __shfl(alpha, 4 * lg + j);
#pragma unroll
        for (int n = 0; n < 4; ++n)
#pragma unroll
            for (int j = 0; j < 4; ++j)
                o[n][j] *= alj[j];

        // ---- PV: P already IS the A-fragment ----
        bf16x8 aP[2];
#pragma unroll
        for (int k2 = 0; k2 < 2; ++k2) {
            bf16x8 t;
#pragma unroll
            for (int j = 0; j < 4; ++j) {
                t[j]     = f2bf(s[2 * k2][j]);
                t[4 + j] = f2bf(s[2 * k2 + 1][j]);
            }
            aP[k2] = t;
        }
#pragma unroll
        for (int k2 = 0; k2 < 2; ++k2)
#pragma unroll
            for (int n = 0; n < 4; ++n)
                o[n] = __builtin_amdgcn_mfma_f32_16x16x32_bf16(
                    aP[k2], cat8(vf[n * 2 + k2][0], vf[n * 2 + k2][1]), o[n], 0, 0, 0);
    }

    // ---- per-wave partials: o[n][j] = O[q=4lg+j][h=n*16+lr]; m/l owned by lane lr (lg==0) ----
#pragma unroll
    for (int n = 0; n < 4; ++n)
#pragma unroll
        for (int j = 0; j < 4; ++j)
            ored[wv][4 * lg + j][n * 16 + lr] = o[n][j];
    if (lg == 0) {
        mred[wv][lr] = m2;
        lred[wv][lr] = l_run;
    }
    __syncthreads();

    // ---- merge 4 waves: thread t -> row r=t>>4, cols 4*(t&15).. ----
    const int r = tid >> 4, c0 = (tid & 15) * 4;
    const float M = fmaxf(fmaxf(mred[0][r], mred[1][r]), fmaxf(mred[2][r], mred[3][r]));
    float sc[4], L = 0.f;
#pragma unroll
    for (int w = 0; w < 4; ++w) {
        sc[w] = exp2f(mred[w][r] - M);
        L += sc[w] * lred[w][r];
    }
    const float inv = 1.f / L;
    float4 res;
#pragma unroll
    for (int u = 0; u < 4; ++u) {
        float acc = sc[0] * ored[0][r][c0 + u] + sc[1] * ored[1][r][c0 + u]
                  + sc[2] * ored[2][r][c0 + u] + sc[3] * ored[3][r][c0 + u];
        (&res.x)[u] = acc * inv;
    }
    *reinterpret_cast<float4*>(&out[((size_t)b * TT + q0 + r) * HH + c0]) = res;
}

extern "C" void kernel_launch(void* const* d_in, const int* in_sizes, int n_in,
                              void* d_out, int out_size, void* d_ws, size_t ws_size,
                              hipStream_t stream) {
    const float* x  = (const float*)d_in[0];
    const float* Wk = (const float*)d_in[1];
    const float* Wq = (const float*)d_in[2];
    const float* Wv = (const float*)d_in[3];
    float* outp = (float*)d_out;

    const size_t n = (size_t)BB * TT * HH; // 1,048,576
    short* kbuf = (short*)d_ws;
    short* qbuf = kbuf + n;
    short* vbuf = qbuf + n;                 // vT layout [B][H][T]
    short* wbf  = vbuf + n;                 // 3*64*1024 bf16 weights

    wconv<<<192, 256, 0, stream>>>(Wk, Wq, Wv, wbf);
    proj_fused<<<256, 256, 0, stream>>>(x, wbf, kbuf, qbuf, vbuf);
    attn_swap<<<1024, 256, 0, stream>>>(qbuf, kbuf, vbuf, outp);
}

// Round 13
// 81.221 us; speedup vs baseline: 1.3678x; 1.3581x over previous
//
#include <hip/hip_runtime.h>
#include <math.h>

#define BB 8
#define TT 2048
#define CC 1024
#define HH 64
constexpr float SC2 = 0.03125f * 1.4426950408889634f; // (1/sqrt(1024)) * log2(e)

typedef __attribute__((ext_vector_type(8))) short bf16x8;
typedef __attribute__((ext_vector_type(8))) short s16x8;
typedef __attribute__((ext_vector_type(4))) short s16x4;
typedef __attribute__((ext_vector_type(4))) float f32x4;

static __device__ __forceinline__ short f2bf(float f) {
    union { float f; unsigned u; } un; un.f = f;
    unsigned r = un.u + 0x7FFFu + ((un.u >> 16) & 1u); // RNE
    return (short)(r >> 16);
}
static __device__ __forceinline__ bf16x8 cat8(s16x4 lo, s16x4 hi) {
    return __builtin_shufflevector(lo, hi, 0, 1, 2, 3, 4, 5, 6, 7);
}

// ---------------- Kernel 0: W fp32 -> bf16 ----------------
__global__ __launch_bounds__(256) void wconv(
    const float* __restrict__ Wk, const float* __restrict__ Wq, const float* __restrict__ Wv,
    short* __restrict__ wbf)
{
    const int i = blockIdx.x * 256 + threadIdx.x;
    const int elem = i * 4;
    const int mat = elem >> 16;
    const int off = elem & 65535;
    const float* W = (mat == 0) ? Wk : (mat == 1) ? Wq : Wv;
    float4 w4 = *reinterpret_cast<const float4*>(&W[off]);
    s16x4 h = { f2bf(w4.x), f2bf(w4.y), f2bf(w4.z), f2bf(w4.w) };
    *reinterpret_cast<s16x4*>(&wbf[elem]) = h;
}

// ---------------- Kernel 1: fused qkv projection, bf16 MFMA ----------------
__global__ __launch_bounds__(256) void proj_fused(
    const float* __restrict__ x, const short* __restrict__ wbf,
    short* __restrict__ ko, short* __restrict__ qo, short* __restrict__ vT)
{
    __shared__ short At[64][68];
    __shared__ short Bt[192][68];

    const int tid  = threadIdx.x;
    const int row0 = blockIdx.x * 64;
    const int wave = tid >> 6, lane = tid & 63;
    const int wm = wave >> 1, wn = wave & 1;
    const int lr = lane & 15, lg = lane >> 4;

    f32x4 acc[2][6] = {};

    for (int k0 = 0; k0 < CC; k0 += 64) {
        __syncthreads();
#pragma unroll
        for (int it = 0; it < 4; ++it) {
            int idx = tid + 256 * it;
            int rr = idx >> 4, c4 = (idx & 15) * 4;
            float4 xv = *reinterpret_cast<const float4*>(&x[(size_t)(row0 + rr) * CC + k0 + c4]);
            s16x4 hv = { f2bf(xv.x), f2bf(xv.y), f2bf(xv.z), f2bf(xv.w) };
            *reinterpret_cast<s16x4*>(&At[rr][c4]) = hv;
        }
#pragma unroll
        for (int it = 0; it < 12; ++it) {
            int idx = tid + 256 * it;
            int rr = idx >> 4, c4 = (idx & 15) * 4;
            *reinterpret_cast<s16x4*>(&Bt[rr][c4]) =
                *reinterpret_cast<const s16x4*>(&wbf[(size_t)rr * CC + k0 + c4]);
        }
        __syncthreads();

#pragma unroll
        for (int kk = 0; kk < 64; kk += 32) {
            bf16x8 aF[2], bF[6];
#pragma unroll
            for (int m = 0; m < 2; ++m) {
                int row = wm * 32 + m * 16 + lr;
                aF[m] = cat8(*reinterpret_cast<const s16x4*>(&At[row][kk + 4 * lg]),
                             *reinterpret_cast<const s16x4*>(&At[row][kk + 16 + 4 * lg]));
            }
#pragma unroll
            for (int n = 0; n < 6; ++n) {
                int brow = wn * 96 + n * 16 + lr;
                bF[n] = cat8(*reinterpret_cast<const s16x4*>(&Bt[brow][kk + 4 * lg]),
                             *reinterpret_cast<const s16x4*>(&Bt[brow][kk + 16 + 4 * lg]));
            }
#pragma unroll
            for (int m = 0; m < 2; ++m)
#pragma unroll
                for (int n = 0; n < 6; ++n)
                    acc[m][n] = __builtin_amdgcn_mfma_f32_16x16x32_bf16(aF[m], bF[n], acc[m][n], 0, 0, 0);
        }
    }

    const int bb = row0 >> 11;
    const int t0 = row0 & 2047;
#pragma unroll
    for (int m = 0; m < 2; ++m)
#pragma unroll
        for (int n = 0; n < 6; ++n) {
            const int col0 = wn * 96 + n * 16;
            const int mat  = col0 >> 6;
            const int hcol = (col0 & 63) + lr;
            const int trow = wm * 32 + m * 16 + 4 * lg;
            if (mat == 2) {
                s16x4 pk = { f2bf(acc[m][n][0]), f2bf(acc[m][n][1]),
                             f2bf(acc[m][n][2]), f2bf(acc[m][n][3]) };
                *reinterpret_cast<s16x4*>(&vT[((size_t)bb * HH + hcol) * TT + t0 + trow]) = pk;
            } else {
                short* o = (mat == 0) ? ko : qo;
#pragma unroll
                for (int j = 0; j < 4; ++j)
                    o[(size_t)(row0 + trow + j) * HH + hcol] = f2bf(acc[m][n][j]);
            }
        }
}

// ---------------- Kernel 2: causal flash attention, shared-LDS K/V, 64-row q-tile ----------------
// grid 256 blocks (jq*8 + b; 1 block/CU) x 256 thr (4 waves x 16 q-rows).
// Per kv-tile: K[64kv][64h] and VT[64h][64t] staged ONCE in LDS (coalesced, XOR-swizzled,
// double-buffered, T14 load-early/write-late); all 4 waves read frags via conflict-free b64.
__global__ __launch_bounds__(256) void attn_tiled(
    const short* __restrict__ q, const short* __restrict__ k,
    const short* __restrict__ vT, float* __restrict__ out)
{
    __shared__ short kl[2][4096];  // [kv][h] swizzled, 128B rows
    __shared__ short vl[2][4096];  // [h][t]  swizzled

    const int tid = threadIdx.x;
    const int w = tid >> 6, lane = tid & 63;
    const int lr = lane & 15, lg = lane >> 4;
    const int b  = blockIdx.x & 7;
    const int jq = blockIdx.x >> 3;       // 0..31, q-rows [64jq, 64jq+64)
    const int nt = jq + 1;

    const short* qb = q  + ((size_t)b * TT + jq * 64 + w * 16) * HH;
    const short* kb = k  + (size_t)b * TT * HH;   // [t][h]
    const short* vb = vT + (size_t)b * HH * TT;   // [h][t]

    // Q B-frags (once)
    bf16x8 aQ[2];
#pragma unroll
    for (int k2 = 0; k2 < 2; ++k2)
        aQ[k2] = cat8(*reinterpret_cast<const s16x4*>(&qb[lr * HH + k2 * 32 + 4 * lg]),
                      *reinterpret_cast<const s16x4*>(&qb[lr * HH + k2 * 32 + 16 + 4 * lg]));

    // staging geometry: 512 16B-chunks per tile; this thread stages chunks (r0,c7),(r1,c7)
    const int r0 = w * 16 + (lane >> 3);          // rows r0 and r0+8
    const int r1 = r0 + 8;
    const int c7 = lane & 7;
    const int swc = (c7 * 8) ^ ((r0 & 7) << 3);   // swizzled col (shorts); r1&7 == r0&7

    f32x4 o[4] = {};
    float m2 = -INFINITY, l_run = 0.f;            // this lane's q-row = w*16 + lr

    s16x8 sk0, sk1, sv0, sv1;

#define LOADG(t_) do {                                                       \
    const short* kt_ = kb + (size_t)(t_) * 64 * HH;                          \
    const short* vt_ = vb + (t_) * 64;                                       \
    sk0 = *reinterpret_cast<const s16x8*>(&kt_[r0 * HH + c7 * 8]);           \
    sk1 = *reinterpret_cast<const s16x8*>(&kt_[r1 * HH + c7 * 8]);           \
    sv0 = *reinterpret_cast<const s16x8*>(&vt_[(size_t)r0 * TT + c7 * 8]);   \
    sv1 = *reinterpret_cast<const s16x8*>(&vt_[(size_t)r1 * TT + c7 * 8]);   \
  } while (0)

#define WRITELDS(bf_) do {                                                   \
    *reinterpret_cast<s16x8*>(&kl[bf_][r0 * 64 + swc]) = sk0;                \
    *reinterpret_cast<s16x8*>(&kl[bf_][r1 * 64 + swc]) = sk1;                \
    *reinterpret_cast<s16x8*>(&vl[bf_][r0 * 64 + swc]) = sv0;                \
    *reinterpret_cast<s16x8*>(&vl[bf_][r1 * 64 + swc]) = sv1;                \
  } while (0)

    LOADG(0);
    WRITELDS(0);
    __syncthreads();

    for (int t = 0; t < nt; ++t) {
        const int cur = t & 1;
        if (t + 1 < nt) LOADG(t + 1);   // issue early; lands during compute

        // ---- S^T = K Q^T : s[n][j] = S[q = w*16+lr][kv = t*64 + n*16 + 4lg + j] ----
        f32x4 s[4] = {};
#pragma unroll
        for (int k2 = 0; k2 < 2; ++k2)
#pragma unroll
            for (int n = 0; n < 4; ++n) {
                const int row = n * 16 + lr;
                const int sw = (row & 7) << 3;
                s16x4 klo = *reinterpret_cast<const s16x4*>(&kl[cur][row * 64 + ((32 * k2 + 4 * lg) ^ sw)]);
                s16x4 khi = *reinterpret_cast<const s16x4*>(&kl[cur][row * 64 + ((32 * k2 + 4 * lg + 16) ^ sw)]);
                s[n] = __builtin_amdgcn_mfma_f32_16x16x32_bf16(cat8(klo, khi), aQ[k2], s[n], 0, 0, 0);
            }

        // causal mask (only diag tile crosses)
        if (t == jq) {
#pragma unroll
            for (int n = 0; n < 4; ++n)
#pragma unroll
                for (int j = 0; j < 4; ++j)
                    if (n * 16 + 4 * lg + j > w * 16 + lr) s[n][j] = -3.0e38f;
        }

        // ---- online softmax: full row in-lane + 2 shuffle rounds ----
        float tm = fmaxf(fmaxf(fmaxf(s[0][0], s[0][1]), fmaxf(s[0][2], s[0][3])),
                         fmaxf(fmaxf(s[1][0], s[1][1]), fmaxf(s[1][2], s[1][3])));
        tm = fmaxf(tm, fmaxf(fmaxf(fmaxf(s[2][0], s[2][1]), fmaxf(s[2][2], s[2][3])),
                             fmaxf(fmaxf(s[3][0], s[3][1]), fmaxf(s[3][2], s[3][3]))));
        tm = fmaxf(tm, __shfl_xor(tm, 16));
        tm = fmaxf(tm, __shfl_xor(tm, 32));

        const float mnew = fmaxf(m2, tm * SC2);
        const float alpha = exp2f(m2 - mnew);
        m2 = mnew;

        float psum = 0.f;
#pragma unroll
        for (int n = 0; n < 4; ++n)
#pragma unroll
            for (int j = 0; j < 4; ++j) {
                float p = exp2f(fmaf(s[n][j], SC2, -mnew));
                s[n][j] = p;
                psum += p;
            }
        psum += __shfl_xor(psum, 16);
        psum += __shfl_xor(psum, 32);
        l_run = l_run * alpha + psum;

        float alj[4];
#pragma unroll
        for (int j = 0; j < 4; ++j) alj[j] = __shfl(alpha, 4 * lg + j);
#pragma unroll
        for (int n = 0; n < 4; ++n)
#pragma unroll
            for (int j = 0; j < 4; ++j)
                o[n][j] *= alj[j];

        // ---- PV: P is the A-frag; V^T frags from LDS ----
        bf16x8 aP[2];
#pragma unroll
        for (int k2 = 0; k2 < 2; ++k2) {
            bf16x8 tt;
#pragma unroll
            for (int j = 0; j < 4; ++j) {
                tt[j]     = f2bf(s[2 * k2][j]);
                tt[4 + j] = f2bf(s[2 * k2 + 1][j]);
            }
            aP[k2] = tt;
        }
#pragma unroll
        for (int k2 = 0; k2 < 2; ++k2)
#pragma unroll
            for (int n = 0; n < 4; ++n) {
                const int row = n * 16 + lr;
                const int sw = (row & 7) << 3;
                s16x4 vlo = *reinterpret_cast<const s16x4*>(&vl[cur][row * 64 + ((32 * k2 + 4 * lg) ^ sw)]);
                s16x4 vhi = *reinterpret_cast<const s16x4*>(&vl[cur][row * 64 + ((32 * k2 + 4 * lg + 16) ^ sw)]);
                o[n] = __builtin_amdgcn_mfma_f32_16x16x32_bf16(aP[k2], cat8(vlo, vhi), o[n], 0, 0, 0);
            }

        if (t + 1 < nt) WRITELDS(cur ^ 1);  // write-late into the other buffer
        __syncthreads();                    // drains loads + publishes LDS
    }
#undef LOADG
#undef WRITELDS

    // ---- direct output: o[n][j] = O[q=w*16+4lg+j][h=n*16+lr] ----
    float linv[4];
#pragma unroll
    for (int j = 0; j < 4; ++j) linv[j] = 1.f / __shfl(l_run, 4 * lg + j);
    float* ob = out + ((size_t)b * TT + jq * 64 + w * 16) * HH;
#pragma unroll
    for (int n = 0; n < 4; ++n)
#pragma unroll
        for (int j = 0; j < 4; ++j)
            ob[(size_t)(4 * lg + j) * HH + n * 16 + lr] = o[n][j] * linv[j];
}

extern "C" void kernel_launch(void* const* d_in, const int* in_sizes, int n_in,
                              void* d_out, int out_size, void* d_ws, size_t ws_size,
                              hipStream_t stream) {
    const float* x  = (const float*)d_in[0];
    const float* Wk = (const float*)d_in[1];
    const float* Wq = (const float*)d_in[2];
    const float* Wv = (const float*)d_in[3];
    float* outp = (float*)d_out;

    const size_t n = (size_t)BB * TT * HH; // 1,048,576
    short* kbuf = (short*)d_ws;
    short* qbuf = kbuf + n;
    short* vbuf = qbuf + n;                 // vT layout [B][H][T]
    short* wbf  = vbuf + n;                 // 3*64*1024 bf16 weights

    wconv<<<192, 256, 0, stream>>>(Wk, Wq, Wv, wbf);
    proj_fused<<<256, 256, 0, stream>>>(x, wbf, kbuf, qbuf, vbuf);
    attn_tiled<<<256, 256, 0, stream>>>(qbuf, kbuf, vbuf, outp);
}

// Round 15
// 68.395 us; speedup vs baseline: 1.6243x; 1.1875x over previous
//
#include <hip/hip_runtime.h>
#include <math.h>

#define BB 8
#define TT 2048
#define CC 1024
#define HH 64
constexpr float SC2 = 0.03125f * 1.4426950408889634f; // (1/sqrt(1024)) * log2(e)

typedef __attribute__((ext_vector_type(8))) short bf16x8;
typedef __attribute__((ext_vector_type(8))) short s16x8;
typedef __attribute__((ext_vector_type(4))) short s16x4;
typedef __attribute__((ext_vector_type(4))) float f32x4;

static __device__ __forceinline__ short f2bf(float f) {
    union { float f; unsigned u; } un; un.f = f;
    unsigned r = un.u + 0x7FFFu + ((un.u >> 16) & 1u); // RNE
    return (short)(r >> 16);
}
static __device__ __forceinline__ bf16x8 cat8(s16x4 lo, s16x4 hi) {
    return __builtin_shufflevector(lo, hi, 0, 1, 2, 3, 4, 5, 6, 7);
}

// ---------------- Kernel 0: W fp32 -> bf16 ----------------
__global__ __launch_bounds__(256) void wconv(
    const float* __restrict__ Wk, const float* __restrict__ Wq, const float* __restrict__ Wv,
    short* __restrict__ wbf)
{
    const int i = blockIdx.x * 256 + threadIdx.x;
    const int elem = i * 4;
    const int mat = elem >> 16;
    const int off = elem & 65535;
    const float* W = (mat == 0) ? Wk : (mat == 1) ? Wq : Wv;
    float4 w4 = *reinterpret_cast<const float4*>(&W[off]);
    s16x4 h = { f2bf(w4.x), f2bf(w4.y), f2bf(w4.z), f2bf(w4.w) };
    *reinterpret_cast<s16x4*>(&wbf[elem]) = h;
}

// ---------------- Kernel 1: fused qkv projection, bf16 MFMA ----------------
__global__ __launch_bounds__(256) void proj_fused(
    const float* __restrict__ x, const short* __restrict__ wbf,
    short* __restrict__ ko, short* __restrict__ qo, short* __restrict__ vT)
{
    __shared__ short At[64][68];
    __shared__ short Bt[192][68];

    const int tid  = threadIdx.x;
    const int row0 = blockIdx.x * 64;
    const int wave = tid >> 6, lane = tid & 63;
    const int wm = wave >> 1, wn = wave & 1;
    const int lr = lane & 15, lg = lane >> 4;

    f32x4 acc[2][6] = {};

    for (int k0 = 0; k0 < CC; k0 += 64) {
        __syncthreads();
#pragma unroll
        for (int it = 0; it < 4; ++it) {
            int idx = tid + 256 * it;
            int rr = idx >> 4, c4 = (idx & 15) * 4;
            float4 xv = *reinterpret_cast<const float4*>(&x[(size_t)(row0 + rr) * CC + k0 + c4]);
            s16x4 hv = { f2bf(xv.x), f2bf(xv.y), f2bf(xv.z), f2bf(xv.w) };
            *reinterpret_cast<s16x4*>(&At[rr][c4]) = hv;
        }
#pragma unroll
        for (int it = 0; it < 12; ++it) {
            int idx = tid + 256 * it;
            int rr = idx >> 4, c4 = (idx & 15) * 4;
            *reinterpret_cast<s16x4*>(&Bt[rr][c4]) =
                *reinterpret_cast<const s16x4*>(&wbf[(size_t)rr * CC + k0 + c4]);
        }
        __syncthreads();

#pragma unroll
        for (int kk = 0; kk < 64; kk += 32) {
            bf16x8 aF[2], bF[6];
#pragma unroll
            for (int m = 0; m < 2; ++m) {
                int row = wm * 32 + m * 16 + lr;
                aF[m] = cat8(*reinterpret_cast<const s16x4*>(&At[row][kk + 4 * lg]),
                             *reinterpret_cast<const s16x4*>(&At[row][kk + 16 + 4 * lg]));
            }
#pragma unroll
            for (int n = 0; n < 6; ++n) {
                int brow = wn * 96 + n * 16 + lr;
                bF[n] = cat8(*reinterpret_cast<const s16x4*>(&Bt[brow][kk + 4 * lg]),
                             *reinterpret_cast<const s16x4*>(&Bt[brow][kk + 16 + 4 * lg]));
            }
#pragma unroll
            for (int m = 0; m < 2; ++m)
#pragma unroll
                for (int n = 0; n < 6; ++n)
                    acc[m][n] = __builtin_amdgcn_mfma_f32_16x16x32_bf16(aF[m], bF[n], acc[m][n], 0, 0, 0);
        }
    }

    const int bb = row0 >> 11;
    const int t0 = row0 & 2047;
#pragma unroll
    for (int m = 0; m < 2; ++m)
#pragma unroll
        for (int n = 0; n < 6; ++n) {
            const int col0 = wn * 96 + n * 16;
            const int mat  = col0 >> 6;
            const int hcol = (col0 & 63) + lr;
            const int trow = wm * 32 + m * 16 + 4 * lg;
            if (mat == 2) {
                s16x4 pk = { f2bf(acc[m][n][0]), f2bf(acc[m][n][1]),
                             f2bf(acc[m][n][2]), f2bf(acc[m][n][3]) };
                *reinterpret_cast<s16x4*>(&vT[((size_t)bb * HH + hcol) * TT + t0 + trow]) = pk;
            } else {
                short* o = (mat == 0) ? ko : qo;
#pragma unroll
                for (int j = 0; j < 4; ++j)
                    o[(size_t)(row0 + trow + j) * HH + hcol] = f2bf(acc[m][n][j]);
            }
        }
}

// ---------------- Kernel 2: causal flash attention, kv-parity split + shared LDS ----------------
// 512 blocks x 256 thr. Block = (jq64, b, s): computes kv tiles jt ≡ s (mod 2), jt <= jq.
// blockIdx mapping pairs heavy (jq>=16) with light (jq<16) on the same CU.
// Writes UNNORMALIZED partials (o, m, l) to workspace; attn_merge combines.
__global__ __launch_bounds__(256) void attn_split(
    const short* __restrict__ q, const short* __restrict__ k,
    const short* __restrict__ vT, float* __restrict__ op,
    float* __restrict__ mm, float* __restrict__ ll)
{
    __shared__ short kl[2][4096];  // [kv][h] swizzled
    __shared__ short vl[2][4096];  // [h][t]  swizzled

    const int tid = threadIdx.x;
    const int w = tid >> 6, lane = tid & 63;
    const int lr = lane & 15, lg = lane >> 4;

    int idx = blockIdx.x, jq, r;
    if (idx < 256) { jq = idx >> 4;              r = idx & 15; }
    else           { jq = 31 - ((idx - 256) >> 4); r = (idx - 256) & 15; }
    const int b = r >> 1, s = r & 1;
    const int cnt = (jq >= s) ? ((jq - s) >> 1) + 1 : 0;

    const short* qb = q  + ((size_t)b * TT + jq * 64 + w * 16) * HH;
    const short* kb = k  + (size_t)b * TT * HH;   // [t][h]
    const short* vb = vT + (size_t)b * HH * TT;   // [h][t]

    bf16x8 aQ[2];
#pragma unroll
    for (int k2 = 0; k2 < 2; ++k2)
        aQ[k2] = cat8(*reinterpret_cast<const s16x4*>(&qb[lr * HH + k2 * 32 + 4 * lg]),
                      *reinterpret_cast<const s16x4*>(&qb[lr * HH + k2 * 32 + 16 + 4 * lg]));

    const int r0 = w * 16 + (lane >> 3);
    const int r1 = r0 + 8;
    const int c7 = lane & 7;
    const int swc = (c7 * 8) ^ ((r0 & 7) << 3);

    f32x4 o[4] = {};
    float m2 = -INFINITY, l_run = 0.f;

    s16x8 sk0, sk1, sv0, sv1;

#define LOADG(t_) do {                                                       \
    const short* kt_ = kb + (size_t)(t_) * 64 * HH;                          \
    const short* vt_ = vb + (t_) * 64;                                       \
    sk0 = *reinterpret_cast<const s16x8*>(&kt_[r0 * HH + c7 * 8]);           \
    sk1 = *reinterpret_cast<const s16x8*>(&kt_[r1 * HH + c7 * 8]);           \
    sv0 = *reinterpret_cast<const s16x8*>(&vt_[(size_t)r0 * TT + c7 * 8]);   \
    sv1 = *reinterpret_cast<const s16x8*>(&vt_[(size_t)r1 * TT + c7 * 8]);   \
  } while (0)

#define WRITELDS(bf_) do {                                                   \
    *reinterpret_cast<s16x8*>(&kl[bf_][r0 * 64 + swc]) = sk0;                \
    *reinterpret_cast<s16x8*>(&kl[bf_][r1 * 64 + swc]) = sk1;                \
    *reinterpret_cast<s16x8*>(&vl[bf_][r0 * 64 + swc]) = sv0;                \
    *reinterpret_cast<s16x8*>(&vl[bf_][r1 * 64 + swc]) = sv1;                \
  } while (0)

    if (cnt > 0) {
        LOADG(s);
        WRITELDS(0);
        __syncthreads();

        for (int u = 0; u < cnt; ++u) {
            const int cur = u & 1;
            const int jt = s + 2 * u;
            if (u + 1 < cnt) LOADG(jt + 2);

            // ---- S^T = K Q^T : s[n][j] = S[q = w*16+lr][kv = jt*64 + n*16 + 4lg + j] ----
            f32x4 sv[4] = {};
#pragma unroll
            for (int k2 = 0; k2 < 2; ++k2)
#pragma unroll
                for (int n = 0; n < 4; ++n) {
                    const int row = n * 16 + lr;
                    const int sw = (row & 7) << 3;
                    s16x4 klo = *reinterpret_cast<const s16x4*>(&kl[cur][row * 64 + ((32 * k2 + 4 * lg) ^ sw)]);
                    s16x4 khi = *reinterpret_cast<const s16x4*>(&kl[cur][row * 64 + ((32 * k2 + 4 * lg + 16) ^ sw)]);
                    sv[n] = __builtin_amdgcn_mfma_f32_16x16x32_bf16(cat8(klo, khi), aQ[k2], sv[n], 0, 0, 0);
                }

            if (jt == jq) { // diag tile
#pragma unroll
                for (int n = 0; n < 4; ++n)
#pragma unroll
                    for (int j = 0; j < 4; ++j)
                        if (n * 16 + 4 * lg + j > w * 16 + lr) sv[n][j] = -3.0e38f;
            }

            float tm = fmaxf(fmaxf(fmaxf(sv[0][0], sv[0][1]), fmaxf(sv[0][2], sv[0][3])),
                             fmaxf(fmaxf(sv[1][0], sv[1][1]), fmaxf(sv[1][2], sv[1][3])));
            tm = fmaxf(tm, fmaxf(fmaxf(fmaxf(sv[2][0], sv[2][1]), fmaxf(sv[2][2], sv[2][3])),
                                 fmaxf(fmaxf(sv[3][0], sv[3][1]), fmaxf(sv[3][2], sv[3][3]))));
            tm = fmaxf(tm, __shfl_xor(tm, 16));
            tm = fmaxf(tm, __shfl_xor(tm, 32));

            const float mnew = fmaxf(m2, tm * SC2);
            const float alpha = exp2f(m2 - mnew);
            m2 = mnew;

            float psum = 0.f;
#pragma unroll
            for (int n = 0; n < 4; ++n)
#pragma unroll
                for (int j = 0; j < 4; ++j) {
                    float p = exp2f(fmaf(sv[n][j], SC2, -mnew));
                    sv[n][j] = p;
                    psum += p;
                }
            psum += __shfl_xor(psum, 16);
            psum += __shfl_xor(psum, 32);
            l_run = l_run * alpha + psum;

            float alj[4];
#pragma unroll
            for (int j = 0; j < 4; ++j) alj[j] = __shfl(alpha, 4 * lg + j);
#pragma unroll
            for (int n = 0; n < 4; ++n)
#pragma unroll
                for (int j = 0; j < 4; ++j)
                    o[n][j] *= alj[j];

            bf16x8 aP[2];
#pragma unroll
            for (int k2 = 0; k2 < 2; ++k2) {
                bf16x8 tt;
#pragma unroll
                for (int j = 0; j < 4; ++j) {
                    tt[j]     = f2bf(sv[2 * k2][j]);
                    tt[4 + j] = f2bf(sv[2 * k2 + 1][j]);
                }
                aP[k2] = tt;
            }
#pragma unroll
            for (int k2 = 0; k2 < 2; ++k2)
#pragma unroll
                for (int n = 0; n < 4; ++n) {
                    const int row = n * 16 + lr;
                    const int sw = (row & 7) << 3;
                    s16x4 vlo = *reinterpret_cast<const s16x4*>(&vl[cur][row * 64 + ((32 * k2 + 4 * lg) ^ sw)]);
                    s16x4 vhi = *reinterpret_cast<const s16x4*>(&vl[cur][row * 64 + ((32 * k2 + 4 * lg + 16) ^ sw)]);
                    o[n] = __builtin_amdgcn_mfma_f32_16x16x32_bf16(aP[k2], cat8(vlo, vhi), o[n], 0, 0, 0);
                }

            if (u + 1 < cnt) WRITELDS(cur ^ 1);
            __syncthreads();
        }
    }
#undef LOADG
#undef WRITELDS

    // ---- write UNNORMALIZED partials ----
    float* opb = op + (((size_t)s * BB + b) * TT + jq * 64 + w * 16) * HH;
#pragma unroll
    for (int n = 0; n < 4; ++n)
#pragma unroll
        for (int j = 0; j < 4; ++j)
            opb[(size_t)(4 * lg + j) * HH + n * 16 + lr] = o[n][j];
    if (lg == 0) {
        const size_t mi = ((size_t)s * BB + b) * TT + jq * 64 + w * 16 + lr;
        mm[mi] = m2;
        ll[mi] = l_run;
    }
}

// ---------------- Kernel 3: merge the two kv-parity partials ----------------
// 256 blocks x 256 thr; thread handles 16 floats of one row.
__global__ __launch_bounds__(256) void attn_merge(
    const float* __restrict__ op, const float* __restrict__ mm,
    const float* __restrict__ ll, float* __restrict__ out)
{
    const int t = blockIdx.x * 256 + threadIdx.x; // 65536
    const int row = t >> 2;                       // b*TT + trow (16384 rows)
    const int seg = (t & 3) * 16;

    const float m0 = mm[row],             m1 = mm[BB * TT + row];
    const float l0 = ll[row],             l1 = ll[BB * TT + row];
    const float M  = fmaxf(m0, m1);
    const float e0 = exp2f(m0 - M), e1 = exp2f(m1 - M);
    const float inv = 1.f / (e0 * l0 + e1 * l1);

    const float* p0 = op + (size_t)row * HH + seg;
    const float* p1 = p0 + (size_t)BB * TT * HH;
    float* po = out + (size_t)row * HH + seg;
#pragma unroll
    for (int u = 0; u < 4; ++u) {
        float4 a = *reinterpret_cast<const float4*>(p0 + 4 * u);
        float4 c = *reinterpret_cast<const float4*>(p1 + 4 * u);
        float4 rr = { (e0 * a.x + e1 * c.x) * inv, (e0 * a.y + e1 * c.y) * inv,
                      (e0 * a.z + e1 * c.z) * inv, (e0 * a.w + e1 * c.w) * inv };
        *reinterpret_cast<float4*>(po + 4 * u) = rr;
    }
}

extern "C" void kernel_launch(void* const* d_in, const int* in_sizes, int n_in,
                              void* d_out, int out_size, void* d_ws, size_t ws_size,
                              hipStream_t stream) {
    const float* x  = (const float*)d_in[0];
    const float* Wk = (const float*)d_in[1];
    const float* Wq = (const float*)d_in[2];
    const float* Wv = (const float*)d_in[3];
    float* outp = (float*)d_out;

    const size_t n = (size_t)BB * TT * HH; // 1,048,576
    short* kbuf = (short*)d_ws;
    short* qbuf = kbuf + n;
    short* vbuf = qbuf + n;                 // vT layout [B][H][T]
    short* wbf  = vbuf + n;                 // 3*64*1024 bf16 weights (196,608 shorts)
    float* op   = (float*)(wbf + 196608);   // [2][B][T][H] f32 partials (8 MB)
    float* mm   = op + 2 * n;               // [2][B][T]
    float* ll   = mm + 2 * BB * TT;

    wconv<<<192, 256, 0, stream>>>(Wk, Wq, Wv, wbf);
    proj_fused<<<256, 256, 0, stream>>>(x, wbf, kbuf, qbuf, vbuf);
    attn_split<<<512, 256, 0, stream>>>(qbuf, kbuf, vbuf, op, mm, ll);
    attn_merge<<<256, 256, 0, stream>>>(op, mm, ll, outp);
}

// Round 18
// 55.033 us; speedup vs baseline: 2.0187x; 1.2428x over previous
//
#include <hip/hip_runtime.h>
#include <math.h>

#define BB 8
#define TT 2048
#define CC 1024
#define HH 64
constexpr float SC2 = 0.03125f * 1.4426950408889634f; // (1/sqrt(1024)) * log2(e)

typedef __attribute__((ext_vector_type(8))) short bf16x8;
typedef __attribute__((ext_vector_type(8))) short s16x8;
typedef __attribute__((ext_vector_type(4))) short s16x4;
typedef __attribute__((ext_vector_type(4))) float f32x4;

static __device__ __forceinline__ short f2bf(float f) {
    union { float f; unsigned u; } un; un.f = f;
    unsigned r = un.u + 0x7FFFu + ((un.u >> 16) & 1u); // RNE
    return (short)(r >> 16);
}
static __device__ __forceinline__ bf16x8 cat8(s16x4 lo, s16x4 hi) {
    return __builtin_shufflevector(lo, hi, 0, 1, 2, 3, 4, 5, 6, 7);
}

// ---------------- Kernel 0: W fp32 -> bf16 ----------------
__global__ __launch_bounds__(256) void wconv(
    const float* __restrict__ Wk, const float* __restrict__ Wq, const float* __restrict__ Wv,
    short* __restrict__ wbf)
{
    const int i = blockIdx.x * 256 + threadIdx.x;
    const int elem = i * 4;
    const int mat = elem >> 16;
    const int off = elem & 65535;
    const float* W = (mat == 0) ? Wk : (mat == 1) ? Wq : Wv;
    float4 w4 = *reinterpret_cast<const float4*>(&W[off]);
    s16x4 h = { f2bf(w4.x), f2bf(w4.y), f2bf(w4.z), f2bf(w4.w) };
    *reinterpret_cast<s16x4*>(&wbf[elem]) = h;
}

// ---------------- Kernel 1: fused qkv projection, 512 blocks x 32 rows, dbuf LDS ----------------
// 2 blocks/CU (64.5KB LDS each). Wave wv computes all 32 rows x cols [48wv, 48wv+48).
// T14 pipeline: global->reg loads at compute top, LDS writes after compute, 1 barrier/K-step.
__global__ __launch_bounds__(256) void proj_fused(
    const float* __restrict__ x, const short* __restrict__ wbf,
    short* __restrict__ ko, short* __restrict__ qo, short* __restrict__ vT)
{
    __shared__ short At[2][32][72];   // stride 72: 16B-aligned rows, 2-way (free) frag reads
    __shared__ short Bt[2][192][72];

    const int tid  = threadIdx.x;
    const int row0 = blockIdx.x * 32;
    const int wv = tid >> 6, lane = tid & 63;
    const int lr = lane & 15, lg = lane >> 4;

    // staging geometry
    const int ar  = tid >> 4;            // A rows: chunks tid, tid+256 -> rows ar, ar+16
    const int ac4 = (tid & 15) * 4;
    const int br_ = tid >> 3;            // B rows: chunks tid+256*it -> rows br_+32*it
    const int bc8 = (tid & 7) * 8;

    f32x4 acc[2][3] = {};
    float4 ax0, ax1;
    s16x8 bw[6];

#define PLOADG(k0_) do {                                                               \
    ax0 = *reinterpret_cast<const float4*>(&x[(size_t)(row0 + ar) * CC + (k0_) + ac4]);       \
    ax1 = *reinterpret_cast<const float4*>(&x[(size_t)(row0 + ar + 16) * CC + (k0_) + ac4]);  \
    _Pragma("unroll")                                                                  \
    for (int it = 0; it < 6; ++it)                                                     \
        bw[it] = *reinterpret_cast<const s16x8*>(&wbf[(size_t)(br_ + 32 * it) * CC + (k0_) + bc8]); \
  } while (0)

#define PWRITE(bf_) do {                                                               \
    s16x4 h0 = { f2bf(ax0.x), f2bf(ax0.y), f2bf(ax0.z), f2bf(ax0.w) };                 \
    s16x4 h1 = { f2bf(ax1.x), f2bf(ax1.y), f2bf(ax1.z), f2bf(ax1.w) };                 \
    *reinterpret_cast<s16x4*>(&At[bf_][ar][ac4]) = h0;                                 \
    *reinterpret_cast<s16x4*>(&At[bf_][ar + 16][ac4]) = h1;                            \
    _Pragma("unroll")                                                                  \
    for (int it = 0; it < 6; ++it)                                                     \
        *reinterpret_cast<s16x8*>(&Bt[bf_][br_ + 32 * it][bc8]) = bw[it];              \
  } while (0)

    PLOADG(0);
    PWRITE(0);
    __syncthreads();

    for (int ks = 0; ks < 16; ++ks) {
        const int cur = ks & 1;
        if (ks + 1 < 16) PLOADG((ks + 1) * 64);

#pragma unroll
        for (int kk = 0; kk < 64; kk += 32) {
            bf16x8 aF[2], bF[3];
#pragma unroll
            for (int m = 0; m < 2; ++m) {
                const int row = m * 16 + lr;
                aF[m] = cat8(*reinterpret_cast<const s16x4*>(&At[cur][row][kk + 4 * lg]),
                             *reinterpret_cast<const s16x4*>(&At[cur][row][kk + 16 + 4 * lg]));
            }
#pragma unroll
            for (int n = 0; n < 3; ++n) {
                const int brow = wv * 48 + n * 16 + lr;
                bF[n] = cat8(*reinterpret_cast<const s16x4*>(&Bt[cur][brow][kk + 4 * lg]),
                             *reinterpret_cast<const s16x4*>(&Bt[cur][brow][kk + 16 + 4 * lg]));
            }
#pragma unroll
            for (int m = 0; m < 2; ++m)
#pragma unroll
                for (int n = 0; n < 3; ++n)
                    acc[m][n] = __builtin_amdgcn_mfma_f32_16x16x32_bf16(aF[m], bF[n], acc[m][n], 0, 0, 0);
        }

        if (ks + 1 < 16) PWRITE(cur ^ 1);
        __syncthreads();
    }
#undef PLOADG
#undef PWRITE

    const int bb = row0 >> 11;
    const int t0 = row0 & 2047;
#pragma unroll
    for (int m = 0; m < 2; ++m)
#pragma unroll
        for (int n = 0; n < 3; ++n) {
            const int col0 = wv * 48 + n * 16;    // 16-aligned; within one matrix
            const int mat  = col0 >> 6;
            const int hcol = (col0 & 63) + lr;
            const int trow = m * 16 + 4 * lg;
            if (mat == 2) {
                s16x4 pk = { f2bf(acc[m][n][0]), f2bf(acc[m][n][1]),
                             f2bf(acc[m][n][2]), f2bf(acc[m][n][3]) };
                *reinterpret_cast<s16x4*>(&vT[((size_t)bb * HH + hcol) * TT + t0 + trow]) = pk;
            } else {
                short* o = (mat == 0) ? ko : qo;
#pragma unroll
                for (int j = 0; j < 4; ++j)
                    o[(size_t)(row0 + trow + j) * HH + hcol] = f2bf(acc[m][n][j]);
            }
        }
}

// ---------------- Kernel 2: causal flash attention, kv parity-4 split + shared LDS ----------------
// 1024 blocks (4/CU) x 256 thr. Block = (jq, b, s): kv tiles jt ≡ s (mod 4), jt <= jq.
// blockIdx mapping mixes heavy/light jq on each CU. Unnormalized partials -> attn_merge4.
__global__ __launch_bounds__(256) void attn_split(
    const short* __restrict__ q, const short* __restrict__ k,
    const short* __restrict__ vT, float* __restrict__ op,
    float* __restrict__ mm, float* __restrict__ ll)
{
    __shared__ short kl[2][4096];  // [kv][h] swizzled
    __shared__ short vl[2][4096];  // [h][t]  swizzled

    const int tid = threadIdx.x;
    const int w = tid >> 6, lane = tid & 63;
    const int lr = lane & 15, lg = lane >> 4;

    int idx = blockIdx.x, jq, r;
    if (idx < 512) { jq = idx >> 5;                r = idx & 31; }
    else           { jq = 31 - ((idx - 512) >> 5); r = (idx - 512) & 31; }
    const int b = r >> 2, s = r & 3;
    const int cnt = (jq >= s) ? ((jq - s) >> 2) + 1 : 0;

    const short* qb = q  + ((size_t)b * TT + jq * 64 + w * 16) * HH;
    const short* kb = k  + (size_t)b * TT * HH;   // [t][h]
    const short* vb = vT + (size_t)b * HH * TT;   // [h][t]

    bf16x8 aQ[2];
#pragma unroll
    for (int k2 = 0; k2 < 2; ++k2)
        aQ[k2] = cat8(*reinterpret_cast<const s16x4*>(&qb[lr * HH + k2 * 32 + 4 * lg]),
                      *reinterpret_cast<const s16x4*>(&qb[lr * HH + k2 * 32 + 16 + 4 * lg]));

    const int r0 = w * 16 + (lane >> 3);
    const int r1 = r0 + 8;
    const int c7 = lane & 7;
    const int swc = (c7 * 8) ^ ((r0 & 7) << 3);

    f32x4 o[4] = {};
    float m2 = -INFINITY, l_run = 0.f;

    s16x8 sk0, sk1, sv0, sv1;

#define LOADG(t_) do {                                                       \
    const short* kt_ = kb + (size_t)(t_) * 64 * HH;                          \
    const short* vt_ = vb + (t_) * 64;                                       \
    sk0 = *reinterpret_cast<const s16x8*>(&kt_[r0 * HH + c7 * 8]);           \
    sk1 = *reinterpret_cast<const s16x8*>(&kt_[r1 * HH + c7 * 8]);           \
    sv0 = *reinterpret_cast<const s16x8*>(&vt_[(size_t)r0 * TT + c7 * 8]);   \
    sv1 = *reinterpret_cast<const s16x8*>(&vt_[(size_t)r1 * TT + c7 * 8]);   \
  } while (0)

#define WRITELDS(bf_) do {                                                   \
    *reinterpret_cast<s16x8*>(&kl[bf_][r0 * 64 + swc]) = sk0;                \
    *reinterpret_cast<s16x8*>(&kl[bf_][r1 * 64 + swc]) = sk1;                \
    *reinterpret_cast<s16x8*>(&vl[bf_][r0 * 64 + swc]) = sv0;                \
    *reinterpret_cast<s16x8*>(&vl[bf_][r1 * 64 + swc]) = sv1;                \
  } while (0)

    if (cnt > 0) {
        LOADG(s);
        WRITELDS(0);
        __syncthreads();

        for (int u = 0; u < cnt; ++u) {
            const int cur = u & 1;
            const int jt = s + 4 * u;
            if (u + 1 < cnt) LOADG(jt + 4);

            // ---- S^T = K Q^T : sv[n][j] = S[q = w*16+lr][kv = jt*64 + n*16 + 4lg + j] ----
            f32x4 sv[4] = {};
#pragma unroll
            for (int k2 = 0; k2 < 2; ++k2)
#pragma unroll
                for (int n = 0; n < 4; ++n) {
                    const int row = n * 16 + lr;
                    const int sw = (row & 7) << 3;
                    s16x4 klo = *reinterpret_cast<const s16x4*>(&kl[cur][row * 64 + ((32 * k2 + 4 * lg) ^ sw)]);
                    s16x4 khi = *reinterpret_cast<const s16x4*>(&kl[cur][row * 64 + ((32 * k2 + 4 * lg + 16) ^ sw)]);
                    sv[n] = __builtin_amdgcn_mfma_f32_16x16x32_bf16(cat8(klo, khi), aQ[k2], sv[n], 0, 0, 0);
                }

            if (jt == jq) { // diag tile
#pragma unroll
                for (int n = 0; n < 4; ++n)
#pragma unroll
                    for (int j = 0; j < 4; ++j)
                        if (n * 16 + 4 * lg + j > w * 16 + lr) sv[n][j] = -3.0e38f;
            }

            float tm = fmaxf(fmaxf(fmaxf(sv[0][0], sv[0][1]), fmaxf(sv[0][2], sv[0][3])),
                             fmaxf(fmaxf(sv[1][0], sv[1][1]), fmaxf(sv[1][2], sv[1][3])));
            tm = fmaxf(tm, fmaxf(fmaxf(fmaxf(sv[2][0], sv[2][1]), fmaxf(sv[2][2], sv[2][3])),
                                 fmaxf(fmaxf(sv[3][0], sv[3][1]), fmaxf(sv[3][2], sv[3][3]))));
            tm = fmaxf(tm, __shfl_xor(tm, 16));
            tm = fmaxf(tm, __shfl_xor(tm, 32));

            const float mnew = fmaxf(m2, tm * SC2);
            const float alpha = exp2f(m2 - mnew);
            m2 = mnew;

            float psum = 0.f;
#pragma unroll
            for (int n = 0; n < 4; ++n)
#pragma unroll
                for (int j = 0; j < 4; ++j) {
                    float p = exp2f(fmaf(sv[n][j], SC2, -mnew));
                    sv[n][j] = p;
                    psum += p;
                }
            psum += __shfl_xor(psum, 16);
            psum += __shfl_xor(psum, 32);
            l_run = l_run * alpha + psum;

            float alj[4];
#pragma unroll
            for (int j = 0; j < 4; ++j) alj[j] = __shfl(alpha, 4 * lg + j);
#pragma unroll
            for (int n = 0; n < 4; ++n)
#pragma unroll
                for (int j = 0; j < 4; ++j)
                    o[n][j] *= alj[j];

            bf16x8 aP[2];
#pragma unroll
            for (int k2 = 0; k2 < 2; ++k2) {
                bf16x8 tt;
#pragma unroll
                for (int j = 0; j < 4; ++j) {
                    tt[j]     = f2bf(sv[2 * k2][j]);
                    tt[4 + j] = f2bf(sv[2 * k2 + 1][j]);
                }
                aP[k2] = tt;
            }
#pragma unroll
            for (int k2 = 0; k2 < 2; ++k2)
#pragma unroll
                for (int n = 0; n < 4; ++n) {
                    const int row = n * 16 + lr;
                    const int sw = (row & 7) << 3;
                    s16x4 vlo = *reinterpret_cast<const s16x4*>(&vl[cur][row * 64 + ((32 * k2 + 4 * lg) ^ sw)]);
                    s16x4 vhi = *reinterpret_cast<const s16x4*>(&vl[cur][row * 64 + ((32 * k2 + 4 * lg + 16) ^ sw)]);
                    o[n] = __builtin_amdgcn_mfma_f32_16x16x32_bf16(aP[k2], cat8(vlo, vhi), o[n], 0, 0, 0);
                }

            if (u + 1 < cnt) WRITELDS(cur ^ 1);
            __syncthreads();
        }
    }
#undef LOADG
#undef WRITELDS

    // ---- write UNNORMALIZED partials ----
    float* opb = op + (((size_t)s * BB + b) * TT + jq * 64 + w * 16) * HH;
#pragma unroll
    for (int n = 0; n < 4; ++n)
#pragma unroll
        for (int j = 0; j < 4; ++j)
            opb[(size_t)(4 * lg + j) * HH + n * 16 + lr] = o[n][j];
    if (lg == 0) {
        const size_t mi = ((size_t)s * BB + b) * TT + jq * 64 + w * 16 + lr;
        mm[mi] = m2;
        ll[mi] = l_run;
    }
}

// ---------------- Kernel 3: merge the four kv-parity partials ----------------
__global__ __launch_bounds__(256) void attn_merge4(
    const float* __restrict__ op, const float* __restrict__ mm,
    const float* __restrict__ ll, float* __restrict__ out)
{
    const int t = blockIdx.x * 256 + threadIdx.x; // 65536
    const int row = t >> 2;                       // b*TT + trow
    const int seg = (t & 3) * 16;
    const size_t BT = (size_t)BB * TT;

    float mw[4], lw[4];
#pragma unroll
    for (int w = 0; w < 4; ++w) { mw[w] = mm[w * BT + row]; lw[w] = ll[w * BT + row]; }
    const float M = fmaxf(fmaxf(mw[0], mw[1]), fmaxf(mw[2], mw[3]));
    float ew[4], L = 0.f;
#pragma unroll
    for (int w = 0; w < 4; ++w) { ew[w] = exp2f(mw[w] - M); L += ew[w] * lw[w]; }
    const float inv = 1.f / L;

    float* po = out + (size_t)row * HH + seg;
#pragma unroll
    for (int u = 0; u < 4; ++u) {
        float acc[4] = {0.f, 0.f, 0.f, 0.f};
#pragma unroll
        for (int w = 0; w < 4; ++w) {
            float4 a = *reinterpret_cast<const float4*>(&op[(w * BT + row) * HH + seg + 4 * u]);
            acc[0] += ew[w] * a.x; acc[1] += ew[w] * a.y;
            acc[2] += ew[w] * a.z; acc[3] += ew[w] * a.w;
        }
        float4 rr = { acc[0] * inv, acc[1] * inv, acc[2] * inv, acc[3] * inv };
        *reinterpret_cast<float4*>(po + 4 * u) = rr;
    }
}

extern "C" void kernel_launch(void* const* d_in, const int* in_sizes, int n_in,
                              void* d_out, int out_size, void* d_ws, size_t ws_size,
                              hipStream_t stream) {
    const float* x  = (const float*)d_in[0];
    const float* Wk = (const float*)d_in[1];
    const float* Wq = (const float*)d_in[2];
    const float* Wv = (const float*)d_in[3];
    float* outp = (float*)d_out;

    const size_t n = (size_t)BB * TT * HH; // 1,048,576
    short* kbuf = (short*)d_ws;
    short* qbuf = kbuf + n;
    short* vbuf = qbuf + n;                 // vT layout [B][H][T]
    short* wbf  = vbuf + n;                 // 3*64*1024 bf16 weights (196,608 shorts)
    float* op   = (float*)(wbf + 196608);   // [4][B][T][H] f32 partials (16 MB)
    float* mm   = op + 4 * n;               // [4][B][T]
    float* ll   = mm + 4 * BB * TT;

    wconv<<<192, 256, 0, stream>>>(Wk, Wq, Wv, wbf);
    proj_fused<<<512, 256, 0, stream>>>(x, wbf, kbuf, qbuf, vbuf);
    attn_split<<<1024, 256, 0, stream>>>(qbuf, kbuf, vbuf, op, mm, ll);
    attn_merge4<<<256, 256, 0, stream>>>(op, mm, ll, outp);
}